// Round 1
// baseline (881.461 us; speedup 1.0000x reference)
//
#include <hip/hip_runtime.h>
#include <cstddef>

#define NE 16384
#define NN 4096
#define CSTR 4416   // C columns: [G:4096][Bias(be2):64][gh:192][mroot:64]

__device__ __forceinline__ float lrelu(float v){ return v >= 0.f ? v : 0.01f*v; }
__device__ __forceinline__ float sigm(float v){ return 1.f/(1.f + expf(-v)); }

// ---------------- setup: B_aug, WihT, h0, he, deg ----------------
__global__ __launch_bounds__(256) void setup_kernel(
    const float* __restrict__ x, const float* __restrict__ ea,
    const int* __restrict__ ei,
    const float* __restrict__ W0, const float* __restrict__ b0,
    const float* __restrict__ We1, const float* __restrict__ be1,
    const float* __restrict__ We2, const float* __restrict__ be2,
    const float* __restrict__ root, const float* __restrict__ Whh,
    const float* __restrict__ Wih,
    float* __restrict__ Baug, float* __restrict__ WihT,
    float* __restrict__ h, float* __restrict__ he, int* __restrict__ deg)
{
    int t = blockIdx.x*256 + threadIdx.x;   // grid: 4096x256 = 1048576
    {   // he: [E,64]  lrelu(edge_attr @ We1 + be1)
        int e = t >> 6, f = t & 63;
        float v = be1[f];
        #pragma unroll
        for (int d = 0; d < 4; ++d) v += ea[e*4+d]*We1[d*64+f];
        he[t] = lrelu(v);
    }
    if (t < 64*CSTR) {  // B_aug[d][c]
        int d = t / CSTR, c = t - d*CSTR;
        float v;
        if (c < 4096)      v = We2[(c>>6)*4096 + d*64 + (c&63)];   // G cols (k*64+f)
        else if (c < 4160) v = be2[d*64 + (c-4096)];               // Bias cols
        else if (c < 4352) v = Whh[(c-4160)*64 + d];               // gh cols (Whh^T)
        else               v = root[d*64 + (c-4352)];              // mroot cols
        Baug[t] = v;
    }
    if (t < NN*64) {    // h0 = lrelu(x @ W0 + b0)
        int n = t >> 6, f = t & 63;
        float v = b0[f];
        #pragma unroll
        for (int d = 0; d < 3; ++d) v += x[n*3+d]*W0[d*64+f];
        h[t] = lrelu(v);
    }
    if (t < 12288) { int k = t / 192; WihT[t] = Wih[(t - k*192)*64 + k]; }  // WihT[k][g]
    if (t < NE) atomicAdd(&deg[ei[NE + t]], 1);
}

__global__ __launch_bounds__(256) void inv_kernel(const int* __restrict__ deg,
                                                  float* __restrict__ inv_deg)
{
    int t = blockIdx.x*256 + threadIdx.x;
    if (t < NN) inv_deg[t] = 1.f / fmaxf((float)deg[t], 1.f);
}

// ---------------- per-iteration big GEMM: C[4096][4416] = h @ B_aug ----------------
// tile 128x128, thread 8x8. A (h) transposed in LDS; B streamed from L2.
__global__ __launch_bounds__(256) void gemm_big(
    const float* __restrict__ h, const float* __restrict__ Baug,
    float* __restrict__ C, float* __restrict__ agg)
{
    __shared__ float As[64][132];   // As[k][m], row-pad 132 (16B-aligned rows)
    int t = threadIdx.x;
    int bx = blockIdx.x;            // 0..34 col tile
    int by = blockIdx.y;            // 0..31 row tile
    int m0 = by*128, c0 = bx*128;

    if (bx == 0) {                  // zero agg (262144 floats over 32 blocks)
        float* a = agg + by*8192;
        #pragma unroll
        for (int i = 0; i < 32; ++i) a[t + i*256] = 0.f;
    }
    // stage A transposed: 128 rows x 64 k
    #pragma unroll
    for (int i = 0; i < 8; ++i) {
        int idx4 = t + i*256;            // float4 index 0..2047
        int r = idx4 >> 4;               // row 0..127
        int kc = (idx4 & 15) * 4;        // k 0..60
        const float4 v = *(const float4*)(h + (size_t)(m0 + r)*64 + kc);
        As[kc+0][r] = v.x; As[kc+1][r] = v.y; As[kc+2][r] = v.z; As[kc+3][r] = v.w;
    }
    __syncthreads();

    int tx = t & 15, ty = t >> 4;
    int c_lo = c0 + tx*4, c_hi = c0 + 64 + tx*4;
    bool hi_ok = (c0 + 64) < CSTR;       // uniform per block

    float acc[8][8];
    #pragma unroll
    for (int i = 0; i < 8; ++i)
        #pragma unroll
        for (int j = 0; j < 8; ++j) acc[i][j] = 0.f;

    #pragma unroll 8
    for (int k = 0; k < 64; ++k) {
        float4 a0 = *(const float4*)&As[k][ty*4];
        float4 a1 = *(const float4*)&As[k][64 + ty*4];
        float4 b0 = *(const float4*)(Baug + (size_t)k*CSTR + c_lo);
        float4 b1 = hi_ok ? *(const float4*)(Baug + (size_t)k*CSTR + c_hi)
                          : make_float4(0.f,0.f,0.f,0.f);
        float av[8] = {a0.x,a0.y,a0.z,a0.w,a1.x,a1.y,a1.z,a1.w};
        float bv[8] = {b0.x,b0.y,b0.z,b0.w,b1.x,b1.y,b1.z,b1.w};
        #pragma unroll
        for (int i = 0; i < 8; ++i)
            #pragma unroll
            for (int j = 0; j < 8; ++j) acc[i][j] += av[i]*bv[j];
    }

    #pragma unroll
    for (int i = 0; i < 8; ++i) {
        int m = m0 + (i>>2)*64 + ty*4 + (i&3);
        float* Cr = C + (size_t)m*CSTR;
        *(float4*)(Cr + c_lo) = make_float4(acc[i][0],acc[i][1],acc[i][2],acc[i][3]);
        if (hi_ok)
            *(float4*)(Cr + c_hi) = make_float4(acc[i][4],acc[i][5],acc[i][6],acc[i][7]);
    }
}

// ---------------- per-iteration edge kernel: msg + scatter ----------------
__global__ __launch_bounds__(256) void edge_kernel(
    const float* __restrict__ C, const float* __restrict__ he,
    const int* __restrict__ ei, float* __restrict__ agg)
{
    __shared__ float hs[256];
    int t = threadIdx.x;
    int e0 = blockIdx.x*4;
    hs[t] = he[(size_t)e0*64 + t];
    __syncthreads();
    int w = t >> 6, f = t & 63;
    int e = e0 + w;
    int src = ei[e], dst = ei[NE + e];
    const float* Cs = C + (size_t)src*CSTR;
    float m = Cs[4096 + f];              // Bias[src,f]
    #pragma unroll 8
    for (int k = 0; k < 64; ++k) m += hs[w*64+k] * Cs[k*64 + f];
    atomicAdd(&agg[(size_t)dst*64 + f], m);
}

// ---------------- per-iteration node kernel: m -> gi GEMM -> GRU (in-place h) ----
__global__ __launch_bounds__(256) void node_kernel(
    const float* __restrict__ C, const float* __restrict__ agg,
    const float* __restrict__ inv_deg, const float* __restrict__ conv_b,
    const float* __restrict__ WihT, const float* __restrict__ bih,
    const float* __restrict__ bhh, float* __restrict__ h)
{
    __shared__ float WT[64][196];   // WihT[k][g], pad 196
    __shared__ float mT[64][18];    // m transposed [k][node], 16 nodes, pad 18
    int t = threadIdx.x;
    int n0 = blockIdx.x * 16;
    #pragma unroll
    for (int i = 0; i < 48; ++i) {  // stage WihT (12288)
        int idx = t + i*256;
        int k = idx / 192;
        WT[k][idx - k*192] = WihT[idx];
    }
    #pragma unroll
    for (int i = 0; i < 4; ++i) {   // compute & stage m (16x64)
        int idx = t + i*256;
        int n = idx >> 6, d = idx & 63;
        int gn = n0 + n;
        float v = agg[(size_t)gn*64 + d]*inv_deg[gn]
                + C[(size_t)gn*CSTR + 4352 + d] + conv_b[d];
        mT[d][n] = lrelu(v);
    }
    __syncthreads();

    int tx = t & 31, ty = t >> 5;   // tx: gate pair, ty: node pair
    float acc[2][2][3] = {};
    for (int k = 0; k < 64; ++k) {
        float2 a  = *(float2*)&mT[k][ty*2];
        float2 br = *(float2*)&WT[k][tx*2];
        float2 bz = *(float2*)&WT[k][64 + tx*2];
        float2 bn = *(float2*)&WT[k][128 + tx*2];
        acc[0][0][0] += a.x*br.x; acc[0][1][0] += a.x*br.y;
        acc[1][0][0] += a.y*br.x; acc[1][1][0] += a.y*br.y;
        acc[0][0][1] += a.x*bz.x; acc[0][1][1] += a.x*bz.y;
        acc[1][0][1] += a.y*bz.x; acc[1][1][1] += a.y*bz.y;
        acc[0][0][2] += a.x*bn.x; acc[0][1][2] += a.x*bn.y;
        acc[1][0][2] += a.y*bn.x; acc[1][1][2] += a.y*bn.y;
    }
    #pragma unroll
    for (int i = 0; i < 2; ++i) {
        int n = n0 + ty*2 + i;
        const float* Cn = C + (size_t)n*CSTR;
        #pragma unroll
        for (int j = 0; j < 2; ++j) {
            int g = tx*2 + j;
            float ir  = acc[i][j][0] + bih[g];
            float iz  = acc[i][j][1] + bih[64+g];
            float in_ = acc[i][j][2] + bih[128+g];
            float ghr = Cn[4160 + g]       + bhh[g];
            float ghz = Cn[4160 + 64 + g]  + bhh[64+g];
            float ghn = Cn[4160 + 128 + g] + bhh[128+g];
            float r  = sigm(ir + ghr);
            float z  = sigm(iz + ghz);
            float nn = tanhf(in_ + r*ghn);
            float ho = h[(size_t)n*64 + g];
            h[(size_t)n*64 + g] = (1.f - z)*nn + z*ho;
        }
    }
}

// ---------------- finale: Set2Set(1 step) + lin_out ----------------
__global__ void q_kernel(const float* __restrict__ lbih,
                         const float* __restrict__ lbhh, float* __restrict__ q)
{
    int g = threadIdx.x;  // 64
    float gi = lbih[g]       + lbhh[g];
    float gg = lbih[128+g]   + lbhh[128+g];
    float go = lbih[192+g]   + lbhh[192+g];
    float cl = sigm(gi)*tanhf(gg);          // cl0 = 0, so forget-gate term drops
    q[g] = sigm(go)*tanhf(cl);
}

__global__ __launch_bounds__(256) void e_kernel(
    const float* __restrict__ h, const float* __restrict__ q, float* __restrict__ e)
{
    __shared__ float qs[64];
    int t = threadIdx.x;
    if (t < 64) qs[t] = q[t];
    __syncthreads();
    int w = t >> 6, f = t & 63;
    int n = blockIdx.x*4 + w;
    float p = h[(size_t)n*64 + f]*qs[f];
    #pragma unroll
    for (int off = 32; off; off >>= 1) p += __shfl_xor(p, off);
    if (f == 0) e[n] = p;
}

__global__ __launch_bounds__(256) void pool_kernel(
    const float* __restrict__ h, const float* __restrict__ e,
    const int* __restrict__ batch, const float* __restrict__ q,
    const float* __restrict__ Wout, const float* __restrict__ bout,
    float* __restrict__ out)
{
    __shared__ float red[256];
    __shared__ float rp[64];
    __shared__ float smx, ssum;
    int g = blockIdx.x, t = threadIdx.x;

    float mx = -1e30f;
    for (int n = t; n < NN; n += 256)
        if (batch[n] == g) mx = fmaxf(mx, e[n]);
    red[t] = mx; __syncthreads();
    for (int s = 128; s; s >>= 1) { if (t < s) red[t] = fmaxf(red[t], red[t+s]); __syncthreads(); }
    if (t == 0) smx = red[0];
    __syncthreads();
    float lmx = smx;

    float sm = 0.f;
    for (int n = t; n < NN; n += 256)
        if (batch[n] == g) sm += expf(e[n]-lmx);
    red[t] = sm; __syncthreads();
    for (int s = 128; s; s >>= 1) { if (t < s) red[t] += red[t+s]; __syncthreads(); }
    if (t == 0) ssum = red[0];
    __syncthreads();
    float inv_asum = 1.f/ssum;

    int w = t >> 6, f = t & 63;
    float racc = 0.f;
    for (int n = w; n < NN; n += 4)
        if (batch[n] == g) racc += expf(e[n]-lmx) * h[(size_t)n*64 + f];
    red[t] = racc; __syncthreads();
    if (w == 0) rp[f] = (red[f] + red[64+f] + red[128+f] + red[192+f]) * inv_asum;
    __syncthreads();

    if (t < 64) {
        float p0 = q[t]*Wout[t*2]   + rp[t]*Wout[(64+t)*2];
        float p1 = q[t]*Wout[t*2+1] + rp[t]*Wout[(64+t)*2+1];
        #pragma unroll
        for (int off = 32; off; off >>= 1) { p0 += __shfl_xor(p0, off); p1 += __shfl_xor(p1, off); }
        if (t == 0) { out[g*2] = p0 + bout[0]; out[g*2+1] = p1 + bout[1]; }
    }
}

extern "C" void kernel_launch(void* const* d_in, const int* in_sizes, int n_in,
                              void* d_out, int out_size, void* d_ws, size_t ws_size,
                              hipStream_t stream)
{
    const float* x      = (const float*)d_in[0];
    const float* ea     = (const float*)d_in[1];
    const int*   ei     = (const int*)  d_in[2];
    const int*   batch  = (const int*)  d_in[3];
    const float* W0     = (const float*)d_in[4];
    const float* b0     = (const float*)d_in[5];
    const float* We1    = (const float*)d_in[6];
    const float* be1    = (const float*)d_in[7];
    const float* We2    = (const float*)d_in[8];
    const float* be2    = (const float*)d_in[9];
    const float* root   = (const float*)d_in[10];
    const float* conv_b = (const float*)d_in[11];
    const float* Wih    = (const float*)d_in[12];
    const float* Whh    = (const float*)d_in[13];
    const float* bih    = (const float*)d_in[14];
    const float* bhh    = (const float*)d_in[15];
    const float* lbih   = (const float*)d_in[18];
    const float* lbhh   = (const float*)d_in[19];
    const float* Wout   = (const float*)d_in[20];
    const float* bout   = (const float*)d_in[21];
    float* out = (float*)d_out;

    float* W = (float*)d_ws;
    size_t off = 0;
    float* C       = W + off; off += (size_t)NN*CSTR;   // 18,087,936
    float* Baug    = W + off; off += (size_t)64*CSTR;   // 282,624
    float* h       = W + off; off += (size_t)NN*64;
    float* he      = W + off; off += (size_t)NE*64;
    float* agg     = W + off; off += (size_t)NN*64;
    float* WihT    = W + off; off += 12288;
    float* inv_deg = W + off; off += NN;
    float* e       = W + off; off += NN;
    float* q       = W + off; off += 64;
    int*   deg     = (int*)(W + off); off += NN;

    hipMemsetAsync(deg, 0, NN*sizeof(int), stream);
    setup_kernel<<<4096, 256, 0, stream>>>(x, ea, ei, W0, b0, We1, be1, We2, be2,
                                           root, Whh, Wih, Baug, WihT, h, he, deg);
    inv_kernel<<<16, 256, 0, stream>>>(deg, inv_deg);

    for (int it = 0; it < 6; ++it) {
        gemm_big<<<dim3(35, 32), 256, 0, stream>>>(h, Baug, C, agg);
        edge_kernel<<<NE/4, 256, 0, stream>>>(C, he, ei, agg);
        node_kernel<<<NN/16, 256, 0, stream>>>(C, agg, inv_deg, conv_b, WihT, bih, bhh, h);
    }

    q_kernel<<<1, 64, 0, stream>>>(lbih, lbhh, q);
    e_kernel<<<NN/4, 256, 0, stream>>>(h, q, e);
    pool_kernel<<<16, 256, 0, stream>>>(h, e, batch, q, Wout, bout, out);
}

// Round 2
// 657.115 us; speedup vs baseline: 1.3414x; 1.3414x over previous
//
#include <hip/hip_runtime.h>
#include <cstddef>

#define NE 16384
#define NN 4096
#define BG 16
#define CSTR 4416   // C columns: [G:4096][Bias(be2):64][gh:192][mroot:64]

__device__ __forceinline__ float lrelu(float v){ return v >= 0.f ? v : 0.01f*v; }
__device__ __forceinline__ float sigm(float v){ return 1.f/(1.f + expf(-v)); }

// ---------------- setup: B_aug, WihT, h0, he, deg(dst), cnt(src) ----------------
__global__ __launch_bounds__(256) void setup_kernel(
    const float* __restrict__ x, const float* __restrict__ ea,
    const int* __restrict__ ei,
    const float* __restrict__ W0, const float* __restrict__ b0,
    const float* __restrict__ We1, const float* __restrict__ be1,
    const float* __restrict__ We2, const float* __restrict__ be2,
    const float* __restrict__ root, const float* __restrict__ Whh,
    const float* __restrict__ Wih,
    float* __restrict__ Baug, float* __restrict__ WihT,
    float* __restrict__ h, float* __restrict__ he,
    int* __restrict__ deg, int* __restrict__ cnt)
{
    int t = blockIdx.x*256 + threadIdx.x;   // grid: 4096x256 = 1048576
    {   // he: [E,64]  lrelu(edge_attr @ We1 + be1)
        int e = t >> 6, f = t & 63;
        float v = be1[f];
        #pragma unroll
        for (int d = 0; d < 4; ++d) v += ea[e*4+d]*We1[d*64+f];
        he[t] = lrelu(v);
    }
    if (t < 64*CSTR) {  // B_aug[d][c]
        int d = t / CSTR, c = t - d*CSTR;
        float v;
        if (c < 4096)      v = We2[(c>>6)*4096 + d*64 + (c&63)];   // G cols (k*64+f)
        else if (c < 4160) v = be2[d*64 + (c-4096)];               // Bias cols
        else if (c < 4352) v = Whh[(c-4160)*64 + d];               // gh cols (Whh^T)
        else               v = root[d*64 + (c-4352)];              // mroot cols
        Baug[t] = v;
    }
    if (t < NN*64) {    // h0 = lrelu(x @ W0 + b0)
        int n = t >> 6, f = t & 63;
        float v = b0[f];
        #pragma unroll
        for (int d = 0; d < 3; ++d) v += x[n*3+d]*W0[d*64+f];
        h[t] = lrelu(v);
    }
    if (t < 12288) { int k = t / 192; WihT[t] = Wih[(t - k*192)*64 + k]; }  // WihT[k][g]
    if (t < NE) {
        atomicAdd(&deg[ei[NE + t]], 1);   // in-degree (dst) for mean aggr
        atomicAdd(&cnt[ei[t]], 1);        // out-degree (src) for edge sort
    }
}

// ---------------- exclusive scan of cnt[4096] -> offs[4097] (1 block) ----------------
__global__ __launch_bounds__(256) void scan_kernel(const int* __restrict__ cnt,
                                                   int* __restrict__ offs)
{
    __shared__ int ps[256];
    int t = threadIdx.x;
    int base = t*16;
    int loc[16];
    int s = 0;
    #pragma unroll
    for (int i = 0; i < 16; ++i) { loc[i] = s; s += cnt[base+i]; }
    ps[t] = s; __syncthreads();
    for (int off = 1; off < 256; off <<= 1) {
        int v = 0;
        if (t >= off) v = ps[t-off];
        __syncthreads();
        if (t >= off) ps[t] += v;
        __syncthreads();
    }
    int pre = (t == 0) ? 0 : ps[t-1];
    #pragma unroll
    for (int i = 0; i < 16; ++i) offs[base+i] = pre + loc[i];
    if (t == 255) offs[NN] = pre + s;
}

// ---------------- scatter: build src-sorted edge arrays ----------------
__global__ __launch_bounds__(256) void scatter_kernel(
    const int* __restrict__ ei, const int* __restrict__ offs,
    int* __restrict__ cnt,  // consumed as cursor via atomicSub
    int* __restrict__ srcs, int* __restrict__ dsts, int* __restrict__ perm)
{
    int e = blockIdx.x*256 + threadIdx.x;
    if (e >= NE) return;
    int s = ei[e], d = ei[NE + e];
    int old = atomicSub(&cnt[s], 1);
    int pos = offs[s] + old - 1;
    srcs[pos] = s; dsts[pos] = d; perm[pos] = e;
}

// ---------------- inv_deg + per-graph node ranges ----------------
__global__ __launch_bounds__(256) void inv_range_kernel(
    const int* __restrict__ deg, const int* __restrict__ batch,
    float* __restrict__ inv_deg, int* __restrict__ gstart, int* __restrict__ gend)
{
    int n = blockIdx.x*256 + threadIdx.x;   // 16 blocks -> 4096
    if (n >= NN) return;
    inv_deg[n] = 1.f / fmaxf((float)deg[n], 1.f);
    int b  = batch[n];
    int bp = (n == 0)    ? -1 : batch[n-1];
    int bn = (n == NN-1) ? BG : batch[n+1];
    for (int g = bp+1; g <= b; ++g) gstart[g] = n;   // start of b (+ leading empties)
    for (int g = b;   g <  bn; ++g) gend[g]   = n+1; // end of b (+ following empties)
    if (n == 0)    for (int g = 0;   g < b;  ++g) gend[g]   = 0;   // leading empties
    if (n == NN-1) for (int g = b+1; g < BG; ++g) gstart[g] = NN;  // trailing empties
}

// ---------------- per-iteration big GEMM: C[4096][4416] = h @ B_aug ----------------
// tile 128x128, thread 8x8. A (h) transposed in LDS; B streamed from L2.
__global__ __launch_bounds__(256) void gemm_big(
    const float* __restrict__ h, const float* __restrict__ Baug,
    float* __restrict__ C, float* __restrict__ agg)
{
    __shared__ float As[64][132];   // As[k][m], row-pad 132
    int t = threadIdx.x;
    int bx = blockIdx.x;            // 0..34 col tile
    int by = blockIdx.y;            // 0..31 row tile
    int m0 = by*128, c0 = bx*128;

    if (bx == 0) {                  // zero agg (262144 floats over 32 blocks)
        float* a = agg + by*8192;
        #pragma unroll
        for (int i = 0; i < 32; ++i) a[t + i*256] = 0.f;
    }
    #pragma unroll
    for (int i = 0; i < 8; ++i) {   // stage A transposed: 128 rows x 64 k
        int idx4 = t + i*256;
        int r = idx4 >> 4;
        int kc = (idx4 & 15) * 4;
        const float4 v = *(const float4*)(h + (size_t)(m0 + r)*64 + kc);
        As[kc+0][r] = v.x; As[kc+1][r] = v.y; As[kc+2][r] = v.z; As[kc+3][r] = v.w;
    }
    __syncthreads();

    int tx = t & 15, ty = t >> 4;
    int c_lo = c0 + tx*4, c_hi = c0 + 64 + tx*4;
    bool hi_ok = (c0 + 64) < CSTR;

    float acc[8][8];
    #pragma unroll
    for (int i = 0; i < 8; ++i)
        #pragma unroll
        for (int j = 0; j < 8; ++j) acc[i][j] = 0.f;

    #pragma unroll 8
    for (int k = 0; k < 64; ++k) {
        float4 a0 = *(const float4*)&As[k][ty*4];
        float4 a1 = *(const float4*)&As[k][64 + ty*4];
        float4 b0 = *(const float4*)(Baug + (size_t)k*CSTR + c_lo);
        float4 b1 = hi_ok ? *(const float4*)(Baug + (size_t)k*CSTR + c_hi)
                          : make_float4(0.f,0.f,0.f,0.f);
        float av[8] = {a0.x,a0.y,a0.z,a0.w,a1.x,a1.y,a1.z,a1.w};
        float bv[8] = {b0.x,b0.y,b0.z,b0.w,b1.x,b1.y,b1.z,b1.w};
        #pragma unroll
        for (int i = 0; i < 8; ++i)
            #pragma unroll
            for (int j = 0; j < 8; ++j) acc[i][j] += av[i]*bv[j];
    }

    #pragma unroll
    for (int i = 0; i < 8; ++i) {
        int m = m0 + (i>>2)*64 + ty*4 + (i&3);
        float* Cr = C + (size_t)m*CSTR;
        *(float4*)(Cr + c_lo) = make_float4(acc[i][0],acc[i][1],acc[i][2],acc[i][3]);
        if (hi_ok)
            *(float4*)(Cr + c_hi) = make_float4(acc[i][4],acc[i][5],acc[i][6],acc[i][7]);
    }
}

// ---------------- per-iteration edge kernel: msg + scatter (src-sorted) ----------------
__global__ __launch_bounds__(256) void edge_kernel(
    const float* __restrict__ C, const float* __restrict__ he,
    const int* __restrict__ srcs, const int* __restrict__ dsts,
    const int* __restrict__ perm, float* __restrict__ agg)
{
    __shared__ float hs[256];
    int t = threadIdx.x;
    int e0 = blockIdx.x*4;
    int w = t >> 6, f = t & 63;
    int es = e0 + w;
    int pe = perm[es];
    hs[t] = he[(size_t)pe*64 + f];
    int src = srcs[es], dst = dsts[es];
    __syncthreads();
    const float* Cs = C + (size_t)src*CSTR;
    float m = Cs[4096 + f];              // Bias[src,f]
    #pragma unroll 8
    for (int k = 0; k < 64; ++k) m += hs[w*64+k] * Cs[k*64 + f];
    atomicAdd(&agg[(size_t)dst*64 + f], m);
}

// ---------------- per-iteration node kernel: m -> gi GEMM -> GRU (in-place h) ----
__global__ __launch_bounds__(256) void node_kernel(
    const float* __restrict__ C, const float* __restrict__ agg,
    const float* __restrict__ inv_deg, const float* __restrict__ conv_b,
    const float* __restrict__ WihT, const float* __restrict__ bih,
    const float* __restrict__ bhh, float* __restrict__ h)
{
    __shared__ float WT[64][196];
    __shared__ float mT[64][18];
    int t = threadIdx.x;
    int n0 = blockIdx.x * 16;
    #pragma unroll
    for (int i = 0; i < 48; ++i) {
        int idx = t + i*256;
        int k = idx / 192;
        WT[k][idx - k*192] = WihT[idx];
    }
    #pragma unroll
    for (int i = 0; i < 4; ++i) {
        int idx = t + i*256;
        int n = idx >> 6, d = idx & 63;
        int gn = n0 + n;
        float v = agg[(size_t)gn*64 + d]*inv_deg[gn]
                + C[(size_t)gn*CSTR + 4352 + d] + conv_b[d];
        mT[d][n] = lrelu(v);
    }
    __syncthreads();

    int tx = t & 31, ty = t >> 5;
    float acc[2][2][3] = {};
    for (int k = 0; k < 64; ++k) {
        float2 a  = *(float2*)&mT[k][ty*2];
        float2 br = *(float2*)&WT[k][tx*2];
        float2 bz = *(float2*)&WT[k][64 + tx*2];
        float2 bn = *(float2*)&WT[k][128 + tx*2];
        acc[0][0][0] += a.x*br.x; acc[0][1][0] += a.x*br.y;
        acc[1][0][0] += a.y*br.x; acc[1][1][0] += a.y*br.y;
        acc[0][0][1] += a.x*bz.x; acc[0][1][1] += a.x*bz.y;
        acc[1][0][1] += a.y*bz.x; acc[1][1][1] += a.y*bz.y;
        acc[0][0][2] += a.x*bn.x; acc[0][1][2] += a.x*bn.y;
        acc[1][0][2] += a.y*bn.x; acc[1][1][2] += a.y*bn.y;
    }
    #pragma unroll
    for (int i = 0; i < 2; ++i) {
        int n = n0 + ty*2 + i;
        const float* Cn = C + (size_t)n*CSTR;
        #pragma unroll
        for (int j = 0; j < 2; ++j) {
            int g = tx*2 + j;
            float ir  = acc[i][j][0] + bih[g];
            float iz  = acc[i][j][1] + bih[64+g];
            float in_ = acc[i][j][2] + bih[128+g];
            float r  = sigm(ir  + Cn[4160 + g]       + bhh[g]);
            float z  = sigm(iz  + Cn[4160 + 64 + g]  + bhh[64+g]);
            float nn = tanhf(in_ + r*(Cn[4160 + 128 + g] + bhh[128+g]));
            float ho = h[(size_t)n*64 + g];
            h[(size_t)n*64 + g] = (1.f - z)*nn + z*ho;
        }
    }
}

// ---------------- finale ----------------
__device__ __forceinline__ float q_val(const float* lbih, const float* lbhh, int g)
{
    float gi = lbih[g]     + lbhh[g];
    float gg = lbih[128+g] + lbhh[128+g];
    float go = lbih[192+g] + lbhh[192+g];
    return sigm(go)*tanhf(sigm(gi)*tanhf(gg));   // hl0=cl0=q_star0=0
}

__global__ __launch_bounds__(256) void e_kernel(
    const float* __restrict__ h, const float* __restrict__ lbih,
    const float* __restrict__ lbhh, float* __restrict__ e)
{
    __shared__ float qs[64];
    int t = threadIdx.x;
    if (t < 64) qs[t] = q_val(lbih, lbhh, t);
    __syncthreads();
    int w = t >> 6, f = t & 63;
    int n = blockIdx.x*4 + w;
    float p = h[(size_t)n*64 + f]*qs[f];
    #pragma unroll
    for (int off = 32; off; off >>= 1) p += __shfl_xor(p, off);
    if (f == 0) e[n] = p;
}

__global__ __launch_bounds__(1024) void pool_kernel(
    const float* __restrict__ h, float* __restrict__ e,
    const int* __restrict__ gstart, const int* __restrict__ gend,
    const float* __restrict__ lbih, const float* __restrict__ lbhh,
    const float* __restrict__ Wout, const float* __restrict__ bout,
    float* __restrict__ out)
{
    __shared__ float red[1024];
    __shared__ float rp[64];
    __shared__ float sval;
    int g = blockIdx.x, t = threadIdx.x;
    int s = gstart[g], en = gend[g];

    float mx = -1e30f;
    for (int n = s+t; n < en; n += 1024) mx = fmaxf(mx, e[n]);
    red[t] = mx; __syncthreads();
    for (int st = 512; st; st >>= 1) { if (t < st) red[t] = fmaxf(red[t], red[t+st]); __syncthreads(); }
    if (t == 0) sval = red[0];
    __syncthreads();
    float lmx = sval;
    __syncthreads();

    float sm = 0.f;
    for (int n = s+t; n < en; n += 1024) { float a = expf(e[n]-lmx); e[n] = a; sm += a; }
    red[t] = sm; __syncthreads();
    for (int st = 512; st; st >>= 1) { if (t < st) red[t] += red[t+st]; __syncthreads(); }
    if (t == 0) sval = (red[0] > 0.f) ? 1.f/red[0] : 0.f;
    __syncthreads();
    float inv_asum = sval;
    __syncthreads();

    int w = t >> 6, f = t & 63;
    float racc = 0.f;
    for (int n = s+w; n < en; n += 16) racc += e[n]*h[(size_t)n*64 + f];
    red[t] = racc; __syncthreads();
    if (w == 0) {
        float a = 0.f;
        #pragma unroll
        for (int i = 0; i < 16; ++i) a += red[i*64 + f];
        rp[f] = a*inv_asum;
    }
    __syncthreads();

    if (t < 64) {
        float qv = q_val(lbih, lbhh, t);
        float p0 = qv*Wout[t*2]   + rp[t]*Wout[(64+t)*2];
        float p1 = qv*Wout[t*2+1] + rp[t]*Wout[(64+t)*2+1];
        #pragma unroll
        for (int off = 32; off; off >>= 1) { p0 += __shfl_xor(p0, off); p1 += __shfl_xor(p1, off); }
        if (t == 0) { out[g*2] = p0 + bout[0]; out[g*2+1] = p1 + bout[1]; }
    }
}

extern "C" void kernel_launch(void* const* d_in, const int* in_sizes, int n_in,
                              void* d_out, int out_size, void* d_ws, size_t ws_size,
                              hipStream_t stream)
{
    const float* x      = (const float*)d_in[0];
    const float* ea     = (const float*)d_in[1];
    const int*   ei     = (const int*)  d_in[2];
    const int*   batch  = (const int*)  d_in[3];
    const float* W0     = (const float*)d_in[4];
    const float* b0     = (const float*)d_in[5];
    const float* We1    = (const float*)d_in[6];
    const float* be1    = (const float*)d_in[7];
    const float* We2    = (const float*)d_in[8];
    const float* be2    = (const float*)d_in[9];
    const float* root   = (const float*)d_in[10];
    const float* conv_b = (const float*)d_in[11];
    const float* Wih    = (const float*)d_in[12];
    const float* Whh    = (const float*)d_in[13];
    const float* bih    = (const float*)d_in[14];
    const float* bhh    = (const float*)d_in[15];
    const float* lbih   = (const float*)d_in[18];
    const float* lbhh   = (const float*)d_in[19];
    const float* Wout   = (const float*)d_in[20];
    const float* bout   = (const float*)d_in[21];
    float* out = (float*)d_out;

    float* W = (float*)d_ws;
    size_t off = 0;
    float* C       = W + off; off += (size_t)NN*CSTR;   // 18,087,936
    float* Baug    = W + off; off += (size_t)64*CSTR;
    float* h       = W + off; off += (size_t)NN*64;
    float* he      = W + off; off += (size_t)NE*64;
    float* agg     = W + off; off += (size_t)NN*64;
    float* WihT    = W + off; off += 12288;
    float* inv_deg = W + off; off += NN;
    float* e       = W + off; off += NN;
    int*   deg     = (int*)(W + off); off += NN;   // deg+cnt contiguous: one memset
    int*   cnt     = (int*)(W + off); off += NN;
    int*   offs    = (int*)(W + off); off += NN+1;
    int*   srcs    = (int*)(W + off); off += NE;
    int*   dsts    = (int*)(W + off); off += NE;
    int*   perm    = (int*)(W + off); off += NE;
    int*   gstart  = (int*)(W + off); off += BG;
    int*   gend    = (int*)(W + off); off += BG;

    hipMemsetAsync(deg, 0, 2*NN*sizeof(int), stream);
    setup_kernel<<<4096, 256, 0, stream>>>(x, ea, ei, W0, b0, We1, be1, We2, be2,
                                           root, Whh, Wih, Baug, WihT, h, he, deg, cnt);
    scan_kernel<<<1, 256, 0, stream>>>(cnt, offs);
    scatter_kernel<<<64, 256, 0, stream>>>(ei, offs, cnt, srcs, dsts, perm);
    inv_range_kernel<<<16, 256, 0, stream>>>(deg, batch, inv_deg, gstart, gend);

    for (int it = 0; it < 6; ++it) {
        gemm_big<<<dim3(35, 32), 256, 0, stream>>>(h, Baug, C, agg);
        edge_kernel<<<NE/4, 256, 0, stream>>>(C, he, srcs, dsts, perm, agg);
        node_kernel<<<NN/16, 256, 0, stream>>>(C, agg, inv_deg, conv_b, WihT, bih, bhh, h);
    }

    e_kernel<<<NN/4, 256, 0, stream>>>(h, lbih, lbhh, e);
    pool_kernel<<<BG, 1024, 0, stream>>>(h, e, gstart, gend, lbih, lbhh, Wout, bout, out);
}